// Round 10
// baseline (343.752 us; speedup 1.0000x reference)
//
#include <hip/hip_runtime.h>
#include <math.h>

// Problem constants
constexpr int Bn  = 8;
constexpr int Cn  = 96;
constexpr int Hn  = 224;
constexpr int Wn  = 224;
constexpr int HWn = Hn * Wn;      // 50176
constexpr int Nn  = 56 * 56;      // 3136 (subsampled grid)
constexpr int On  = 192;          // output channels = 2*Cn

typedef unsigned short u16;
typedef __attribute__((ext_vector_type(8))) short bfrag;   // 8 bf16 (4 VGPRs)
typedef __attribute__((ext_vector_type(4))) float f32x4;   // MFMA accumulator

__device__ inline u16 f2b(float f) {                        // fp32 -> bf16 (RNE)
  unsigned int u = __float_as_uint(f);
  u += 0x7fffu + ((u >> 16) & 1u);
  return (u16)(u >> 16);
}

__device__ inline float gelu_f(float v) {
  // tanh-form GELU via sigmoid
  float u2 = v * fmaf(0.0713548162f, v * v, 1.5957691216f);
  u2 = fminf(fmaxf(u2, -80.f), 80.f);
  float e = __expf(u2);
  return v * e * __builtin_amdgcn_rcpf(e + 1.0f);
}

// ---------------- q gather (bf16): qb[b][n][c] = x[b][c][4h'][4w'] ----------------
__global__ __launch_bounds__(256) void k_build_q16(const float* __restrict__ x,
                                                   u16* __restrict__ qb) {
  int idx = blockIdx.x * 256 + threadIdx.x;   // ((b*Nn+n)*Cn + c)
  int c = idx % Cn;
  int t = idx / Cn;
  int n = t % Nn;
  int b = t / Nn;
  int hp = n / 56, wp = n - hp * 56;
  qb[idx] = f2b(x[((b * Cn + c) * Hn + hp * 4) * Wn + wp * 4]);
}

// ---------------- weight cast (bf16, same [o][c] layout) ----------------
__global__ __launch_bounds__(256) void k_wt16(const float* __restrict__ w,
                                              u16* __restrict__ wb) {
  int idx = blockIdx.x * 256 + threadIdx.x;
  wb[idx] = f2b(w[idx]);
}

// ---------------- flash-style self-attention, bf16 MFMA, K-split x4 ----------------
// (unchanged from round 5 — validated)
__global__ __launch_bounds__(256) void k_flash(const u16* __restrict__ qb,
                                               float* __restrict__ part) {
  __shared__ __align__(16) char smem[18944];
  u16* ksm = (u16*)smem;             // 16*7*64 = 7168 u16 = 14336 B
  u16* pl  = (u16*)(smem + 14336);   // [32][72] bf16 P staging = 4608 B
  float* ored = (float*)smem;        // end-of-kernel overlay (14336 B, exact fit)

  const int tid  = threadIdx.x;
  const int lane = tid & 63;
  const int wid  = tid >> 6;
  const int r = lane & 15, g = lane >> 4;
  const int wq = wid & 1, wk = wid >> 1;
  const int tile = blockIdx.x, b = blockIdx.y, kseg = blockIdx.z;
  const float scale = 0.10206207262f;  // 96^-0.5

  const int tbeg = kseg * 12;
  const int tend = (kseg == 3) ? 49 : (kseg + 1) * 12;

  // ones-column tiles (cblk = 6): col 96 = 1.0, cols 97..111 = 0. Written once.
  if (tid < 64) {
    int m = tid;
    int base = ((m >> 2) * 7 + 6) * 64 + (m & 3) * 16;
    uint4 a0 = {0x00003F80u, 0u, 0u, 0u};   // low u16 = bf16 1.0
    uint4 z0 = {0u, 0u, 0u, 0u};
    *(uint4*)&ksm[base] = a0;
    *(uint4*)&ksm[base + 8] = z0;
  }

  // Q fragments straight from bf16 global
  const u16* qp = qb + (size_t)(b * Nn + tile * 32 + wq * 16 + r) * Cn;
  bfrag aq[3];
#pragma unroll
  for (int ks = 0; ks < 3; ++ks) aq[ks] = *(const bfrag*)(qp + ks * 32 + g * 8);

  f32x4 of[7];
#pragma unroll
  for (int i = 0; i < 7; ++i) of[i] = (f32x4){0.f, 0.f, 0.f, 0.f};

  const uint4* q16 = (const uint4*)(qb + (size_t)b * Nn * Cn);  // [3136][12] uint4

  // tr-read base (bytes): subtile (mblk = wk*8+g*2, cblk = nf) anchor + 8*col
  const int vbase = (wk * 8 + g * 2) * 896 + 8 * r;   // + tt*896 + nf*128

  for (int ti = tbeg; ti < tend; ++ti) {
    __syncthreads();
    // stage K-tile rows ti*64..+63 into subtiled layout (uint4 writes only)
#pragma unroll
    for (int i = 0; i < 3; ++i) {
      int f = tid + i * 256;            // 0..767 = 64 rows x 12 chunks
      int row = f / 12, cb = f - row * 12;
      uint4 v = q16[(size_t)(ti * 64 + row) * 12 + cb];
      int off = ((row >> 2) * 7 + (cb >> 1)) * 64 + (row & 3) * 16 + (cb & 1) * 8;
      *(uint4*)&ksm[off] = v;
    }
    __syncthreads();

    // S strip 16x32: rows wq*16+, cols wk*32+
    f32x4 s0 = {0.f, 0.f, 0.f, 0.f}, s1 = {0.f, 0.f, 0.f, 0.f};
    const int mc0 = wk * 32 + r, mc1 = mc0 + 16;
#pragma unroll
    for (int ks = 0; ks < 3; ++ks) {
      int o0 = ((mc0 >> 2) * 7 + ks * 2 + (g >> 1)) * 64 + (mc0 & 3) * 16 + (g & 1) * 8;
      int o1 = ((mc1 >> 2) * 7 + ks * 2 + (g >> 1)) * 64 + (mc1 & 3) * 16 + (g & 1) * 8;
      bfrag bk0 = *(const bfrag*)&ksm[o0];
      bfrag bk1 = *(const bfrag*)&ksm[o1];
      s0 = __builtin_amdgcn_mfma_f32_16x16x32_bf16(aq[ks], bk0, s0, 0, 0, 0);
      s1 = __builtin_amdgcn_mfma_f32_16x16x32_bf16(aq[ks], bk1, s1, 0, 0, 0);
    }

    // exp (scale folded) -> P staging
#pragma unroll
    for (int reg = 0; reg < 4; ++reg) {
      int prow = wq * 16 + 4 * g + reg;
      pl[prow * 72 + wk * 32 + r]      = f2b(__expf(s0[reg] * scale));
      pl[prow * 72 + wk * 32 + 16 + r] = f2b(__expf(s1[reg] * scale));
    }

    // PV B-frags via hardware transpose read:
    //   lane(r,g) elem j of (nf,tt) = V[wk*32 + g*8 + tt*4 + j][nf*16 + r]
    uint2 trv[7][2];
#pragma unroll
    for (int nf = 0; nf < 7; ++nf) {
#pragma unroll
      for (int tt = 0; tt < 2; ++tt) {
        int ab = vbase + tt * 896 + nf * 128;   // bytes
        asm volatile("ds_read_b64_tr_b16 %0, %1" : "=v"(trv[nf][tt]) : "v"(ab));
      }
    }
    bfrag pa = *(const bfrag*)&pl[(wq * 16 + r) * 72 + wk * 32 + g * 8];
    asm volatile("s_waitcnt lgkmcnt(0)" ::: "memory");
    __builtin_amdgcn_sched_barrier(0);
#pragma unroll
    for (int nf = 0; nf < 7; ++nf) {
      union { bfrag f; uint2 u[2]; } cv;
      cv.u[0] = trv[nf][0];
      cv.u[1] = trv[nf][1];
      of[nf] = __builtin_amdgcn_mfma_f32_16x16x32_bf16(pa, cv.f, of[nf], 0, 0, 0);
    }
  }

  // combine wk halves, write partial (unnormalized) [kseg][b][row][c]
  __syncthreads();
  if (wk == 1) {
    int base = (wq * 64 + lane) * 28;
#pragma unroll
    for (int nf = 0; nf < 7; ++nf)
#pragma unroll
      for (int reg = 0; reg < 4; ++reg) ored[base + nf * 4 + reg] = of[nf][reg];
  }
  __syncthreads();
  if (wk == 0) {
    int base = (wq * 64 + lane) * 28;
#pragma unroll
    for (int nf = 0; nf < 7; ++nf)
#pragma unroll
      for (int reg = 0; reg < 4; ++reg) of[nf][reg] += ored[base + nf * 4 + reg];
    float* pb = part + ((size_t)(kseg * Bn + b) * Nn) * 104;
    const int row0 = tile * 32 + wq * 16 + 4 * g;
#pragma unroll
    for (int reg = 0; reg < 4; ++reg) {
      float* pr = pb + (size_t)(row0 + reg) * 104;
#pragma unroll
      for (int nf = 0; nf < 6; ++nf) pr[nf * 16 + r] = of[nf][reg];
      if (r == 0) pr[96] = of[6][reg];
    }
  }
}

// ---------------- K-split reduce: sum 4 partials, normalize, -> bf16 attP ----------------
__global__ __launch_bounds__(256) void k_red(const float* __restrict__ part,
                                             u16* __restrict__ attP) {
  int idx = blockIdx.x * 256 + threadIdx.x;   // (b*Nn+n)*24 + c4
  int c4 = idx % 24;
  int bn = idx / 24;
  constexpr size_t SEG = (size_t)Bn * Nn * 104;
  const float* p0 = part + (size_t)bn * 104;
  float4 s = {0.f, 0.f, 0.f, 0.f};
  float d = 0.f;
#pragma unroll
  for (int ks = 0; ks < 4; ++ks) {
    const float* p = p0 + ks * SEG;
    float4 v = *(const float4*)(p + c4 * 4);
    s.x += v.x; s.y += v.y; s.z += v.z; s.w += v.w;
    d += p[96];
  }
  float inv = 1.0f / d;
  uint2 o;
  o.x = (unsigned)f2b(s.x * inv) | ((unsigned)f2b(s.y * inv) << 16);
  o.y = (unsigned)f2b(s.z * inv) | ((unsigned)f2b(s.w * inv) << 16);
  *(uint2*)(attP + (size_t)bn * 96 + c4 * 4) = o;
}

// ---------------- fused upsample+concat+1x1conv+BN+GELU via MFMA ----------------
// Round-5 validated pipeline (stage -> repack -> MFMA -> direct stores).
// Grid (196, 4): each block owns a 256-PIXEL strip, processed as 4 x 64-px
// sub-iterations (s-loop) x 2 batches. The s-loop makes each input/output row
// touched in 4 temporally-adjacent 256B chunks (= 1KB effective DRAM burst per
// row) instead of isolated 256B chunks at 200KB stride — targets the DRAM
// page-locality limit that pinned all prior variants at ~2.95 TB/s.
__global__ __launch_bounds__(256, 3) void k_convmma(
    const float* __restrict__ x, const u16* __restrict__ attP,
    const u16* __restrict__ wb, const float* __restrict__ cvb,
    const float* __restrict__ gam, const float* __restrict__ bet,
    const float* __restrict__ mu, const float* __restrict__ va,
    float* __restrict__ out) {
  __shared__ u16 ldsT[96 * 68];    // [c][68]  bf16 x-tile, channel-major staging
  __shared__ u16 ldsA[64 * 100];   // [px][100] bf16 x-tile, pixel-major
  __shared__ u16 ldsV[16 * 104];   // [nn][104] bf16 att rows

  const int tid  = threadIdx.x;
  const int lane = tid & 63;
  const int wid  = tid >> 6;
  const int r = lane & 15, g = lane >> 4;
  const int ow = wid * 48;
  const int tile = blockIdx.x;               // 0..195: 256-px strip

  // weight fragments in registers: 18 frags
  bfrag wf[3][6];
#pragma unroll
  for (int of = 0; of < 3; ++of)
#pragma unroll
    for (int ks = 0; ks < 6; ++ks)
      wf[of][ks] = *(const bfrag*)(wb + (ow + of * 16 + r) * On + ks * 32 + g * 8);

  float scv[3], shv[3];
#pragma unroll
  for (int of = 0; of < 3; ++of) {
    int o = ow + of * 16 + r;
    float s = rsqrtf(va[o] + 1e-5f) * gam[o];
    scv[of] = s;
    shv[of] = (cvb[o] - mu[o]) * s + bet[o];
  }

  const int nn_t = tid / 12, cbn = tid - nn_t * 12;
  const float4* x4 = (const float4*)x;

  for (int bi = 0; bi < 2; ++bi) {
    const int b = blockIdx.y * 2 + bi;
    for (int s = 0; s < 4; ++s) {
      const int p0 = tile * 256 + s * 64;
      __syncthreads();
      // phase 1: x (coalesced float4) -> bf16 -> ldsT[c][px]; att rows -> ldsV
#pragma unroll
      for (int i = 0; i < 6; ++i) {
        int f = tid + i * 256;            // 96 c x 16 float4
        int c = f >> 4, q4 = f & 15;
        float4 v = x4[((size_t)(b * Cn + c) * HWn + p0) / 4 + q4];
        uint2 pk;
        pk.x = (unsigned)f2b(v.x) | ((unsigned)f2b(v.y) << 16);
        pk.y = (unsigned)f2b(v.z) | ((unsigned)f2b(v.w) << 16);
        *(uint2*)&ldsT[c * 68 + q4 * 4] = pk;
      }
      if (tid < 192) {
        int p = p0 + nn_t * 4;
        int h = p / Wn, w = p - h * Wn;
        int natt = (h >> 2) * 56 + (w >> 2);
        uint4 v = *(const uint4*)(attP + ((size_t)b * Nn + natt) * Cn + cbn * 8);
        *(uint4*)&ldsV[nn_t * 104 + cbn * 8] = v;
      }
      __syncthreads();
      // phase 2: transpose repack ldsT[c][px] -> ldsA[px][c]
      {
        const int px = tid >> 2, sub = tid & 3;
        uint wbuf[12];
#pragma unroll
        for (int i = 0; i < 12; ++i) {
          unsigned e0 = ldsT[(sub * 24 + 2 * i) * 68 + px];
          unsigned e1 = ldsT[(sub * 24 + 2 * i + 1) * 68 + px];
          wbuf[i] = e0 | (e1 << 16);
        }
#pragma unroll
        for (int i = 0; i < 3; ++i)
          *(uint4*)&ldsA[px * 100 + sub * 24 + i * 8] = *(uint4*)&wbuf[i * 4];
      }
      __syncthreads();
      // phase 3: MFMA
      f32x4 acc[4][3];
#pragma unroll
      for (int pf = 0; pf < 4; ++pf)
#pragma unroll
        for (int of = 0; of < 3; ++of) acc[pf][of] = (f32x4){0.f, 0.f, 0.f, 0.f};

#pragma unroll
      for (int ks = 0; ks < 6; ++ks) {
#pragma unroll
        for (int pf = 0; pf < 4; ++pf) {
          bfrag a;
          if (ks < 3) a = *(const bfrag*)&ldsA[(pf * 16 + r) * 100 + ks * 32 + g * 8];
          else        a = *(const bfrag*)&ldsV[(pf * 4 + (r >> 2)) * 104 + (ks - 3) * 32 + g * 8];
#pragma unroll
          for (int of = 0; of < 3; ++of)
            acc[pf][of] = __builtin_amdgcn_mfma_f32_16x16x32_bf16(a, wf[of][ks], acc[pf][of], 0, 0, 0);
        }
      }
      // epilogue: BN + GELU, direct float4 stores
#pragma unroll
      for (int of = 0; of < 3; ++of) {
        const size_t obase = ((size_t)b * On + ow + of * 16 + r) * (size_t)HWn + p0;
#pragma unroll
        for (int pf = 0; pf < 4; ++pf) {
          float4 o4;
          float* po = (float*)&o4;
#pragma unroll
          for (int reg = 0; reg < 4; ++reg) {
            float v = fmaf(acc[pf][of][reg], scv[of], shv[of]);
            po[reg] = gelu_f(v);
          }
          *reinterpret_cast<float4*>(out + obase + pf * 16 + 4 * g) = o4;
        }
      }
    }
  }
}

extern "C" void kernel_launch(void* const* d_in, const int* in_sizes, int n_in,
                              void* d_out, int out_size, void* d_ws, size_t ws_size,
                              hipStream_t stream) {
  const float* x      = (const float*)d_in[0];
  const float* conv_w = (const float*)d_in[1];
  const float* conv_b = (const float*)d_in[2];
  const float* gam    = (const float*)d_in[3];
  const float* bet    = (const float*)d_in[4];
  const float* mu     = (const float*)d_in[5];
  const float* va     = (const float*)d_in[6];
  float* out = (float*)d_out;

  char* ws = (char*)d_ws;
  constexpr size_t QB16 = (size_t)Bn * Nn * Cn * sizeof(u16);  // 4,816,896
  u16* qb16 = (u16*)(ws);
  u16* attP = (u16*)(ws + QB16);
  u16* wb16 = (u16*)(ws + 2 * QB16);

  // K-split partial scratch: prefer d_ws; fall back to d_out (fully
  // overwritten by k_convmma) if ws is small.
  constexpr size_t PART_OFF   = 16u << 20;                       // 16 MB
  constexpr size_t PART_BYTES = (size_t)4 * Bn * Nn * 104 * 4;   // 41.7 MB
  float* part = (ws_size >= PART_OFF + PART_BYTES) ? (float*)(ws + PART_OFF)
                                                   : out;

  k_build_q16<<<dim3((Bn * Nn * Cn) / 256), dim3(256), 0, stream>>>(x, qb16);
  k_wt16     <<<dim3((On * On) / 256),      dim3(256), 0, stream>>>(conv_w, wb16);
  k_flash    <<<dim3(98, Bn, 4), dim3(256), 0, stream>>>(qb16, part);
  k_red      <<<dim3((Bn * Nn * 24) / 256), dim3(256), 0, stream>>>(part, attP);
  k_convmma  <<<dim3(196, 4), dim3(256), 0, stream>>>(x, attP, wb16, conv_b, gam, bet, mu, va, out);
}

// Round 11
// 282.391 us; speedup vs baseline: 1.2173x; 1.2173x over previous
//
#include <hip/hip_runtime.h>
#include <math.h>

// Problem constants
constexpr int Bn  = 8;
constexpr int Cn  = 96;
constexpr int Hn  = 224;
constexpr int Wn  = 224;
constexpr int HWn = Hn * Wn;      // 50176
constexpr int Nn  = 56 * 56;      // 3136 (subsampled grid)
constexpr int On  = 192;          // output channels = 2*Cn

typedef unsigned short u16;
typedef __attribute__((ext_vector_type(8))) short bfrag;   // 8 bf16 (4 VGPRs)
typedef __attribute__((ext_vector_type(4))) float f32x4;   // MFMA accumulator

__device__ inline u16 f2b(float f) {                        // fp32 -> bf16 (RNE)
  unsigned int u = __float_as_uint(f);
  u += 0x7fffu + ((u >> 16) & 1u);
  return (u16)(u >> 16);
}

__device__ inline float gelu_f(float v) {
  // tanh-form GELU via sigmoid
  float u2 = v * fmaf(0.0713548162f, v * v, 1.5957691216f);
  u2 = fminf(fmaxf(u2, -80.f), 80.f);
  float e = __expf(u2);
  return v * e * __builtin_amdgcn_rcpf(e + 1.0f);
}

// ---------------- q gather (bf16): qb[b][n][c] = x[b][c][4h'][4w'] ----------------
__global__ __launch_bounds__(256) void k_build_q16(const float* __restrict__ x,
                                                   u16* __restrict__ qb) {
  int idx = blockIdx.x * 256 + threadIdx.x;   // ((b*Nn+n)*Cn + c)
  int c = idx % Cn;
  int t = idx / Cn;
  int n = t % Nn;
  int b = t / Nn;
  int hp = n / 56, wp = n - hp * 56;
  qb[idx] = f2b(x[((b * Cn + c) * Hn + hp * 4) * Wn + wp * 4]);
}

// ---------------- weight cast (bf16, same [o][c] layout) ----------------
__global__ __launch_bounds__(256) void k_wt16(const float* __restrict__ w,
                                              u16* __restrict__ wb) {
  int idx = blockIdx.x * 256 + threadIdx.x;
  wb[idx] = f2b(w[idx]);
}

// ---------------- flash-style self-attention, bf16 MFMA, K-split x4 ----------------
// (unchanged from round 5 — validated)
__global__ __launch_bounds__(256) void k_flash(const u16* __restrict__ qb,
                                               float* __restrict__ part) {
  __shared__ __align__(16) char smem[18944];
  u16* ksm = (u16*)smem;             // 16*7*64 = 7168 u16 = 14336 B
  u16* pl  = (u16*)(smem + 14336);   // [32][72] bf16 P staging = 4608 B
  float* ored = (float*)smem;        // end-of-kernel overlay (14336 B, exact fit)

  const int tid  = threadIdx.x;
  const int lane = tid & 63;
  const int wid  = tid >> 6;
  const int r = lane & 15, g = lane >> 4;
  const int wq = wid & 1, wk = wid >> 1;
  const int tile = blockIdx.x, b = blockIdx.y, kseg = blockIdx.z;
  const float scale = 0.10206207262f;  // 96^-0.5

  const int tbeg = kseg * 12;
  const int tend = (kseg == 3) ? 49 : (kseg + 1) * 12;

  // ones-column tiles (cblk = 6): col 96 = 1.0, cols 97..111 = 0. Written once.
  if (tid < 64) {
    int m = tid;
    int base = ((m >> 2) * 7 + 6) * 64 + (m & 3) * 16;
    uint4 a0 = {0x00003F80u, 0u, 0u, 0u};   // low u16 = bf16 1.0
    uint4 z0 = {0u, 0u, 0u, 0u};
    *(uint4*)&ksm[base] = a0;
    *(uint4*)&ksm[base + 8] = z0;
  }

  // Q fragments straight from bf16 global
  const u16* qp = qb + (size_t)(b * Nn + tile * 32 + wq * 16 + r) * Cn;
  bfrag aq[3];
#pragma unroll
  for (int ks = 0; ks < 3; ++ks) aq[ks] = *(const bfrag*)(qp + ks * 32 + g * 8);

  f32x4 of[7];
#pragma unroll
  for (int i = 0; i < 7; ++i) of[i] = (f32x4){0.f, 0.f, 0.f, 0.f};

  const uint4* q16 = (const uint4*)(qb + (size_t)b * Nn * Cn);  // [3136][12] uint4

  // tr-read base (bytes): subtile (mblk = wk*8+g*2, cblk = nf) anchor + 8*col
  const int vbase = (wk * 8 + g * 2) * 896 + 8 * r;   // + tt*896 + nf*128

  for (int ti = tbeg; ti < tend; ++ti) {
    __syncthreads();
    // stage K-tile rows ti*64..+63 into subtiled layout (uint4 writes only)
#pragma unroll
    for (int i = 0; i < 3; ++i) {
      int f = tid + i * 256;            // 0..767 = 64 rows x 12 chunks
      int row = f / 12, cb = f - row * 12;
      uint4 v = q16[(size_t)(ti * 64 + row) * 12 + cb];
      int off = ((row >> 2) * 7 + (cb >> 1)) * 64 + (row & 3) * 16 + (cb & 1) * 8;
      *(uint4*)&ksm[off] = v;
    }
    __syncthreads();

    // S strip 16x32: rows wq*16+, cols wk*32+
    f32x4 s0 = {0.f, 0.f, 0.f, 0.f}, s1 = {0.f, 0.f, 0.f, 0.f};
    const int mc0 = wk * 32 + r, mc1 = mc0 + 16;
#pragma unroll
    for (int ks = 0; ks < 3; ++ks) {
      int o0 = ((mc0 >> 2) * 7 + ks * 2 + (g >> 1)) * 64 + (mc0 & 3) * 16 + (g & 1) * 8;
      int o1 = ((mc1 >> 2) * 7 + ks * 2 + (g >> 1)) * 64 + (mc1 & 3) * 16 + (g & 1) * 8;
      bfrag bk0 = *(const bfrag*)&ksm[o0];
      bfrag bk1 = *(const bfrag*)&ksm[o1];
      s0 = __builtin_amdgcn_mfma_f32_16x16x32_bf16(aq[ks], bk0, s0, 0, 0, 0);
      s1 = __builtin_amdgcn_mfma_f32_16x16x32_bf16(aq[ks], bk1, s1, 0, 0, 0);
    }

    // exp (scale folded) -> P staging
#pragma unroll
    for (int reg = 0; reg < 4; ++reg) {
      int prow = wq * 16 + 4 * g + reg;
      pl[prow * 72 + wk * 32 + r]      = f2b(__expf(s0[reg] * scale));
      pl[prow * 72 + wk * 32 + 16 + r] = f2b(__expf(s1[reg] * scale));
    }

    // PV B-frags via hardware transpose read:
    //   lane(r,g) elem j of (nf,tt) = V[wk*32 + g*8 + tt*4 + j][nf*16 + r]
    uint2 trv[7][2];
#pragma unroll
    for (int nf = 0; nf < 7; ++nf) {
#pragma unroll
      for (int tt = 0; tt < 2; ++tt) {
        int ab = vbase + tt * 896 + nf * 128;   // bytes
        asm volatile("ds_read_b64_tr_b16 %0, %1" : "=v"(trv[nf][tt]) : "v"(ab));
      }
    }
    bfrag pa = *(const bfrag*)&pl[(wq * 16 + r) * 72 + wk * 32 + g * 8];
    asm volatile("s_waitcnt lgkmcnt(0)" ::: "memory");
    __builtin_amdgcn_sched_barrier(0);
#pragma unroll
    for (int nf = 0; nf < 7; ++nf) {
      union { bfrag f; uint2 u[2]; } cv;
      cv.u[0] = trv[nf][0];
      cv.u[1] = trv[nf][1];
      of[nf] = __builtin_amdgcn_mfma_f32_16x16x32_bf16(pa, cv.f, of[nf], 0, 0, 0);
    }
  }

  // combine wk halves, write partial (unnormalized) [kseg][b][row][c]
  __syncthreads();
  if (wk == 1) {
    int base = (wq * 64 + lane) * 28;
#pragma unroll
    for (int nf = 0; nf < 7; ++nf)
#pragma unroll
      for (int reg = 0; reg < 4; ++reg) ored[base + nf * 4 + reg] = of[nf][reg];
  }
  __syncthreads();
  if (wk == 0) {
    int base = (wq * 64 + lane) * 28;
#pragma unroll
    for (int nf = 0; nf < 7; ++nf)
#pragma unroll
      for (int reg = 0; reg < 4; ++reg) of[nf][reg] += ored[base + nf * 4 + reg];
    float* pb = part + ((size_t)(kseg * Bn + b) * Nn) * 104;
    const int row0 = tile * 32 + wq * 16 + 4 * g;
#pragma unroll
    for (int reg = 0; reg < 4; ++reg) {
      float* pr = pb + (size_t)(row0 + reg) * 104;
#pragma unroll
      for (int nf = 0; nf < 6; ++nf) pr[nf * 16 + r] = of[nf][reg];
      if (r == 0) pr[96] = of[6][reg];
    }
  }
}

// ---------------- K-split reduce: sum 4 partials, normalize, -> bf16 attP ----------------
__global__ __launch_bounds__(256) void k_red(const float* __restrict__ part,
                                             u16* __restrict__ attP) {
  int idx = blockIdx.x * 256 + threadIdx.x;   // (b*Nn+n)*24 + c4
  int c4 = idx % 24;
  int bn = idx / 24;
  constexpr size_t SEG = (size_t)Bn * Nn * 104;
  const float* p0 = part + (size_t)bn * 104;
  float4 s = {0.f, 0.f, 0.f, 0.f};
  float d = 0.f;
#pragma unroll
  for (int ks = 0; ks < 4; ++ks) {
    const float* p = p0 + ks * SEG;
    float4 v = *(const float4*)(p + c4 * 4);
    s.x += v.x; s.y += v.y; s.z += v.z; s.w += v.w;
    d += p[96];
  }
  float inv = 1.0f / d;
  uint2 o;
  o.x = (unsigned)f2b(s.x * inv) | ((unsigned)f2b(s.y * inv) << 16);
  o.y = (unsigned)f2b(s.z * inv) | ((unsigned)f2b(s.w * inv) << 16);
  *(uint2*)(attP + (size_t)bn * 96 + c4 * 4) = o;
}

// ---------------- fused upsample+concat+1x1conv+BN+GELU via MFMA ----------------
// Round-5 validated pipeline (stage -> repack -> MFMA -> direct stores) with
// T14 async-stage at a sane register budget: grid (784,1), 8-batch in-block
// loop; batch b+1's global loads (24+4 VGPRs) are issued right after batch b's
// LDS staging writes and consumed next iteration — in flight during
// repack+MFMA+store. launch_bounds(256,3): VGPR cap 170, so the 72-VGPR weight
// fragments stay register-resident (the (256,4)=64-cap forced weight re-reads
// and caused r7/r9's FETCH bloat).
__global__ __launch_bounds__(256, 3) void k_convmma(
    const float* __restrict__ x, const u16* __restrict__ attP,
    const u16* __restrict__ wb, const float* __restrict__ cvb,
    const float* __restrict__ gam, const float* __restrict__ bet,
    const float* __restrict__ mu, const float* __restrict__ va,
    float* __restrict__ out) {
  __shared__ u16 ldsT[96 * 68];    // [c][68]  bf16 x-tile, channel-major staging
  __shared__ u16 ldsA[64 * 100];   // [px][100] bf16 x-tile, pixel-major
  __shared__ u16 ldsV[16 * 104];   // [nn][104] bf16 att rows

  const int tid  = threadIdx.x;
  const int lane = tid & 63;
  const int wid  = tid >> 6;
  const int r = lane & 15, g = lane >> 4;
  const int ow = wid * 48;
  const int tile = blockIdx.x;
  const int p0 = tile * 64;

  // weight fragments in registers: 18 frags = 72 VGPRs
  bfrag wf[3][6];
#pragma unroll
  for (int of = 0; of < 3; ++of)
#pragma unroll
    for (int ks = 0; ks < 6; ++ks)
      wf[of][ks] = *(const bfrag*)(wb + (ow + of * 16 + r) * On + ks * 32 + g * 8);

  float scv[3], shv[3];
#pragma unroll
  for (int of = 0; of < 3; ++of) {
    int o = ow + of * 16 + r;
    float s = rsqrtf(va[o] + 1e-5f) * gam[o];
    scv[of] = s;
    shv[of] = (cvb[o] - mu[o]) * s + bet[o];
  }

  const int nn_t = tid / 12, cbn = tid - nn_t * 12;
  int natt = 0;
  if (tid < 192) {
    int p = p0 + nn_t * 4;
    int h = p / Wn, w = p - h * Wn;
    natt = (h >> 2) * 56 + (w >> 2);
  }

  const float4* x4 = (const float4*)x;
  const int cT = tid >> 4, q4T = tid & 15;   // staging coords (c = cT + 16i)

  // T14 in-flight registers for the next batch's tile
  float4 xr[6];
  uint4  ar;

  // prologue: load batch 0
#pragma unroll
  for (int i = 0; i < 6; ++i)
    xr[i] = x4[((size_t)(cT + i * 16) * HWn + p0) / 4 + q4T];
  if (tid < 192)
    ar = *(const uint4*)(attP + (size_t)natt * Cn + cbn * 8);

  for (int b = 0; b < Bn; ++b) {
    __syncthreads();   // prev iter's LDS consumers done
    // S1: regs -> ldsT (bf16) + ldsV
#pragma unroll
    for (int i = 0; i < 6; ++i) {
      uint2 pk;
      pk.x = (unsigned)f2b(xr[i].x) | ((unsigned)f2b(xr[i].y) << 16);
      pk.y = (unsigned)f2b(xr[i].z) | ((unsigned)f2b(xr[i].w) << 16);
      *(uint2*)&ldsT[(cT + i * 16) * 68 + q4T * 4] = pk;
    }
    if (tid < 192) *(uint4*)&ldsV[nn_t * 104 + cbn * 8] = ar;
    // issue next batch's loads (in flight through repack+MFMA+store)
    if (b < Bn - 1) {
#pragma unroll
      for (int i = 0; i < 6; ++i)
        xr[i] = x4[((size_t)((b + 1) * Cn + cT + i * 16) * HWn + p0) / 4 + q4T];
      if (tid < 192)
        ar = *(const uint4*)(attP + ((size_t)(b + 1) * Nn + natt) * Cn + cbn * 8);
    }
    __syncthreads();
    // S2: transpose repack ldsT[c][px] -> ldsA[px][c]
    {
      const int px = tid >> 2, sub = tid & 3;
      uint wbuf[12];
#pragma unroll
      for (int i = 0; i < 12; ++i) {
        unsigned e0 = ldsT[(sub * 24 + 2 * i) * 68 + px];
        unsigned e1 = ldsT[(sub * 24 + 2 * i + 1) * 68 + px];
        wbuf[i] = e0 | (e1 << 16);
      }
#pragma unroll
      for (int i = 0; i < 3; ++i)
        *(uint4*)&ldsA[px * 100 + sub * 24 + i * 8] = *(uint4*)&wbuf[i * 4];
    }
    __syncthreads();
    // S3: MFMA
    f32x4 acc[4][3];
#pragma unroll
    for (int pf = 0; pf < 4; ++pf)
#pragma unroll
      for (int of = 0; of < 3; ++of) acc[pf][of] = (f32x4){0.f, 0.f, 0.f, 0.f};

#pragma unroll
    for (int ks = 0; ks < 6; ++ks) {
#pragma unroll
      for (int pf = 0; pf < 4; ++pf) {
        bfrag a;
        if (ks < 3) a = *(const bfrag*)&ldsA[(pf * 16 + r) * 100 + ks * 32 + g * 8];
        else        a = *(const bfrag*)&ldsV[(pf * 4 + (r >> 2)) * 104 + (ks - 3) * 32 + g * 8];
#pragma unroll
        for (int of = 0; of < 3; ++of)
          acc[pf][of] = __builtin_amdgcn_mfma_f32_16x16x32_bf16(a, wf[of][ks], acc[pf][of], 0, 0, 0);
      }
    }
    // epilogue: BN + GELU, direct float4 stores
#pragma unroll
    for (int of = 0; of < 3; ++of) {
      const size_t obase = ((size_t)b * On + ow + of * 16 + r) * (size_t)HWn + p0;
#pragma unroll
      for (int pf = 0; pf < 4; ++pf) {
        float4 o4;
        float* po = (float*)&o4;
#pragma unroll
        for (int reg = 0; reg < 4; ++reg) {
          float v = fmaf(acc[pf][of][reg], scv[of], shv[of]);
          po[reg] = gelu_f(v);
        }
        *reinterpret_cast<float4*>(out + obase + pf * 16 + 4 * g) = o4;
      }
    }
  }
}

extern "C" void kernel_launch(void* const* d_in, const int* in_sizes, int n_in,
                              void* d_out, int out_size, void* d_ws, size_t ws_size,
                              hipStream_t stream) {
  const float* x      = (const float*)d_in[0];
  const float* conv_w = (const float*)d_in[1];
  const float* conv_b = (const float*)d_in[2];
  const float* gam    = (const float*)d_in[3];
  const float* bet    = (const float*)d_in[4];
  const float* mu     = (const float*)d_in[5];
  const float* va     = (const float*)d_in[6];
  float* out = (float*)d_out;

  char* ws = (char*)d_ws;
  constexpr size_t QB16 = (size_t)Bn * Nn * Cn * sizeof(u16);  // 4,816,896
  u16* qb16 = (u16*)(ws);
  u16* attP = (u16*)(ws + QB16);
  u16* wb16 = (u16*)(ws + 2 * QB16);

  // K-split partial scratch: prefer d_ws (keeps dirty partial lines out of the
  // output address range — cross-dispatch write-back attribution fix);
  // fall back to d_out (fully overwritten by k_convmma) if ws is small.
  constexpr size_t PART_OFF   = 16u << 20;                       // 16 MB
  constexpr size_t PART_BYTES = (size_t)4 * Bn * Nn * 104 * 4;   // 41.7 MB
  float* part = (ws_size >= PART_OFF + PART_BYTES) ? (float*)(ws + PART_OFF)
                                                   : out;

  k_build_q16<<<dim3((Bn * Nn * Cn) / 256), dim3(256), 0, stream>>>(x, qb16);
  k_wt16     <<<dim3((On * On) / 256),      dim3(256), 0, stream>>>(conv_w, wb16);
  k_flash    <<<dim3(98, Bn, 4), dim3(256), 0, stream>>>(qb16, part);
  k_red      <<<dim3((Bn * Nn * 24) / 256), dim3(256), 0, stream>>>(part, attP);
  k_convmma  <<<dim3(784, 1), dim3(256), 0, stream>>>(x, attP, wb16, conv_b, gam, bet, mu, va, out);
}